// Round 1
// 117.279 us; speedup vs baseline: 1.0163x; 1.0163x over previous
//
#include <hip/hip_runtime.h>

#define N_POINTS 1440
#define N_INT    4000
#define N_GRID   4096
#define BLOCK    256

#define NSEG     16                         // along-ray segments per ray
#define SEG_LEN  (N_INT / NSEG)             // 250 samples per segment
#define RPC      8                          // rays per cluster (adjacent thetas)
#define NCLUST   (N_POINTS / RPC)           // 180 clusters
#define QS       (BLOCK / RPC)              // 32 sample slots per block
#define FULL_ITS (SEG_LEN / QS)             // 7
#define REM_Q    (SEG_LEN - FULL_ITS * QS)  // 26

// Phase 1: each block = 8 adjacent rays x one 250-sample segment.
// Lane layout: t&7 = ray-in-cluster, t>>3 = sample slot, so a wave's 64 lanes
// are 8 consecutive samples x 8 adjacent rays. Adjacent rays are <= 7.5 grid
// cells apart inside the body, so near-vertical rays (the expensive,
// row-crossing ones) share cache lines across the 8 rays at each row:
// ~2-3x fewer lines per wave-load than the old 64-samples-along-one-ray wave.
// Grid = 2880 blocks -> 8 blocks/CU resident (was 5.6), and XCD = b&7 = seg&7
// mixes all ray orientations into every XCD (the old 45-degree-fan-per-XCD
// concentrated the expensive vertical fans on 2 XCDs).
__global__ __launch_bounds__(BLOCK, 8) void wavefront_partial_kernel(
    const float* __restrict__ xp,
    const float* __restrict__ yp,
    const float* __restrict__ SoS,
    const float* __restrict__ thetas,
    const float* __restrict__ x0p,
    const float* __restrict__ y0p,
    const float* __restrict__ dxp,
    const float* __restrict__ dyp,
    const float* __restrict__ Rp,
    const float* __restrict__ v0p,
    float* __restrict__ ws)
{
    const int b = blockIdx.x;
    const int c = b >> 4;          // cluster of 8 adjacent rays
    const int S = b & 15;          // along-ray segment (XCD = b&7 = S&7)
    const int t = threadIdx.x;
    const int r = t & 7;           // ray within cluster
    const int q = t >> 3;          // sample slot (0..31)

    const int p = c * RPC + r;

    const float x  = xp[0];
    const float y  = yp[0];
    const float x0 = x0p[0];
    const float y0 = y0p[0];
    const float dx = dxp[0];
    const float dy = dyp[0];
    const float Rb = Rp[0];
    const float v0 = v0p[0];

    const float theta = thetas[p];

    // Per-ray geometry (redundant across lanes; ~1 us VALU floor total).
    const float rr  = sqrtf(x * x + y * y);
    const float phi = atan2f(x, y);              // reference uses atan2(x, y)
    const float st  = sinf(theta);
    const float ct  = cosf(theta);

    const float sv    = rr * sinf(theta - phi);
    const float arg   = fmaxf(Rb * Rb - sv * sv, 0.0f);
    const float sq    = sqrtf(arg);
    const float l_in  = sq + rr * cosf(theta - phi);
    const float l_out = 2.0f * sq * (cosf(phi - theta) >= 0.0f ? 1.0f : 0.0f);
    const float l     = (rr < Rb) ? l_in : l_out;

    // steps[j] = j/3999; grid index fx(j) = Ax - Bx*j/3999.
    // Samples lie on a chord of the body circle (R=0.05 inside the +-0.06
    // grid): xi,yi in [341,3755], no wrap masks; numpy row-wrap = 4096 - yi.
    const float ds = 1.0f / 3999.0f;
    const float Ax = (x - x0) / dx;
    const float Bx = l * st / dx;
    const float Ay = (y - y0) / dy;
    const float By = l * ct / dy;

    const int   jb     = S * SEG_LEN + q;        // sample index at it=0
    const float s_base = (float)jb * ds;
    const float fx0  = fmaf(-Bx, s_base, Ax);
    const float fy0  = fmaf(-By, s_base, Ay);
    const float nBxd = -Bx * ((float)QS * ds);   // per-iteration delta (32 samples)
    const float nByd = -By * ((float)QS * ds);

    float acc;

#define SAMPLE(itf, vdst)                                            \
    {                                                                \
        const float fx = fmaf((itf), nBxd, fx0);                     \
        const float fy = fmaf((itf), nByd, fy0);                     \
        const int xi = (int)rintf(fx);                               \
        const int yi = (int)rintf(fy);                               \
        const int idx = ((N_GRID - yi) << 12) + xi;                  \
        const float sosv = SoS[idx];                                 \
        vdst = fmaf(-v0, __builtin_amdgcn_rcpf(sosv), 1.0f);         \
    }

    // it=0 carries the j==0 trapezoid end correction (segment 0, slot 0).
    { float v; SAMPLE(0.0f, v); if (S == 0 && q == 0) v *= 0.5f; acc = v; }
#pragma unroll
    for (int it = 1; it < FULL_ITS; ++it) {
        float v; SAMPLE((float)it, v); acc += v;
    }
    if (q < REM_Q) {
        float v; SAMPLE((float)FULL_ITS, v);
        // j==3999 end correction: last segment, last valid slot.
        if (S == NSEG - 1 && q == REM_Q - 1) v *= 0.5f;
        acc += v;
    }
#undef SAMPLE

    // Reduce over the 8 sample slots sharing a ray within the wave
    // (lanes r, r+8, ..., r+56), then across the 4 waves via LDS.
    acc += __shfl_xor(acc, 8, 64);
    acc += __shfl_xor(acc, 16, 64);
    acc += __shfl_xor(acc, 32, 64);

    __shared__ float wsum[4][8];
    if ((t & 63) < 8) wsum[t >> 6][r] = acc;
    __syncthreads();
    if (t < 8) {
        const float tot = (wsum[0][t] + wsum[1][t]) + (wsum[2][t] + wsum[3][t]);
        ws[(c * RPC + t) * NSEG + S] = tot;   // partials[ray][segment]
    }
}

// Phase 2: 1440 threads; sum the 16 segment partials per ray, apply l*ds,
// emit thetas and wf. Reads 92 KB + writes 11.5 KB -> ~2 us.
__global__ __launch_bounds__(BLOCK) void wavefront_combine_kernel(
    const float* __restrict__ xp,
    const float* __restrict__ yp,
    const float* __restrict__ thetas,
    const float* __restrict__ Rp,
    const float* __restrict__ ws,
    float* __restrict__ out)
{
    const int p = blockIdx.x * BLOCK + threadIdx.x;
    if (p >= N_POINTS) return;

    const float x  = xp[0];
    const float y  = yp[0];
    const float Rb = Rp[0];
    const float theta = thetas[p];

    const float rr  = sqrtf(x * x + y * y);
    const float phi = atan2f(x, y);
    const float sv    = rr * sinf(theta - phi);
    const float arg   = fmaxf(Rb * Rb - sv * sv, 0.0f);
    const float sq    = sqrtf(arg);
    const float l_in  = sq + rr * cosf(theta - phi);
    const float l_out = 2.0f * sq * (cosf(phi - theta) >= 0.0f ? 1.0f : 0.0f);
    const float l     = (rr < Rb) ? l_in : l_out;

    const float4* w4 = (const float4*)(ws + p * NSEG);   // 64B-aligned per ray
    const float4 a = w4[0], b4 = w4[1], c4 = w4[2], d4 = w4[3];
    const float tot = (((a.x + a.y) + (a.z + a.w)) + ((b4.x + b4.y) + (b4.z + b4.w)))
                    + (((c4.x + c4.y) + (c4.z + c4.w)) + ((d4.x + d4.y) + (d4.z + d4.w)));

    out[p] = theta;                               // output 0: thetas
    out[N_POINTS + p] = l * (1.0f / 3999.0f) * tot; // output 1: wf
}

extern "C" void kernel_launch(void* const* d_in, const int* in_sizes, int n_in,
                              void* d_out, int out_size, void* d_ws, size_t ws_size,
                              hipStream_t stream) {
    (void)in_sizes; (void)n_in; (void)out_size; (void)ws_size;

    const float* xp     = (const float*)d_in[0];
    const float* yp     = (const float*)d_in[1];
    const float* SoS    = (const float*)d_in[2];
    const float* thetas = (const float*)d_in[3];
    // d_in[4] (steps) unused: steps == linspace(0,1,4000), used analytically.
    const float* x0p    = (const float*)d_in[5];
    const float* y0p    = (const float*)d_in[6];
    const float* dxp    = (const float*)d_in[7];
    const float* dyp    = (const float*)d_in[8];
    const float* Rp     = (const float*)d_in[9];
    const float* v0p    = (const float*)d_in[10];

    float* ws  = (float*)d_ws;     // 1440 x 16 partials = 92160 B
    float* out = (float*)d_out;

    wavefront_partial_kernel<<<NCLUST * NSEG, BLOCK, 0, stream>>>(
        xp, yp, SoS, thetas, x0p, y0p, dxp, dyp, Rp, v0p, ws);
    wavefront_combine_kernel<<<(N_POINTS + BLOCK - 1) / BLOCK, BLOCK, 0, stream>>>(
        xp, yp, thetas, Rp, ws, out);
}